// Round 6
// baseline (190.860 us; speedup 1.0000x reference)
//
#include <hip/hip_runtime.h>
#include <hip/hip_fp16.h>

// Problem: inputs (8, 64, 16, 32, 32) fp32, embedding (1024, 64) fp32
#define THW    16384
#define NTOT   131072
#define KDIM   1024
#define CDIM   64
#define QELEMS 8388608          // 8*64*16*32*32
#define LOSS_OFF 8388608
#define IDX_OFF  8388610
#define BN     128              // queries per block

typedef _Float16 half8   __attribute__((ext_vector_type(8)));
typedef _Float16 half4_t __attribute__((ext_vector_type(4)));
typedef float    f32x4   __attribute__((ext_vector_type(4)));

// ---- prep: zero losses; split E into fp16 hi/lo (lo scaled 2^12) in
// fragment-major order: flat ((tile*2 + kHalf)*64 + lane)*8 + j, where
// lane = lq*16 + ln, code row = tile*16 + ln, c = kHalf*32 + lq*8 + j.
__global__ __launch_bounds__(256) void vq_prep(const float* __restrict__ emb,
        _Float16* __restrict__ EhF, _Float16* __restrict__ ElF,
        float* __restrict__ e2, float* __restrict__ out) {
    const int t = threadIdx.x;
    if (blockIdx.x == 0 && t == 0) { out[LOSS_OFF] = 0.f; out[LOSS_OFF + 1] = 0.f; }
    const int ln   = t >> 4;
    const int g    = t & 15;
    const int tile = blockIdx.x;
    const int row  = tile * 16 + ln;
    const int c0   = g * 4;
    float4 v = *(const float4*)(emb + (size_t)row * CDIM + c0);
    const float xs[4] = {v.x, v.y, v.z, v.w};
    half4_t h, l;
    float s = 0.f;
    #pragma unroll
    for (int j = 0; j < 4; ++j) {
        const _Float16 hj = (_Float16)xs[j];
        const _Float16 lj = (_Float16)((xs[j] - (float)hj) * 4096.0f);
        h[j] = hj; l[j] = lj;
        s = fmaf(xs[j], xs[j], s);
    }
    const int ch = c0 >> 5;
    const int lq = (c0 & 31) >> 3;
    const int j0 = c0 & 7;
    const size_t dst = (((size_t)tile * 2 + ch) * 64 + (lq * 16 + ln)) * 8 + j0;
    *(half4_t*)(EhF + dst) = h;
    *(half4_t*)(ElF + dst) = l;
    #pragma unroll
    for (int off = 1; off < 16; off <<= 1) s += __shfl_xor(s, off, 64);
    if (g == 0) e2[row] = s;
}

// ---- main: each wave scores ALL 128 queries vs its quarter of the codebook ----
__global__ __launch_bounds__(256, 2) void vq_main(const float* __restrict__ in,
        const float* __restrict__ emb,
        const _Float16* __restrict__ EhF, const _Float16* __restrict__ ElF,
        const float* __restrict__ e2, float* __restrict__ out) {

    __shared__ char smem[36352];
    float (*Xs)[68] = (float (*)[68])smem;                 // [128][68] = 34816 B
    float (*Q)[68]  = (float (*)[68])smem;                 // epilogue alias
    float* mv   = (float*)smem;                            // [4][128] alias (2048 B)
    int*   mi   = (int*)(smem + 2048);                     // [4][128] alias (2048 B)
    float* x2p  = (float*)(smem + 34816);                  // [2][128]
    int*   idxs = (int*)(smem + 35840);                    // [128]

    const int tid  = threadIdx.x;
    const int n0   = blockIdx.x * BN;
    const int bb   = n0 >> 14;
    const int thw0 = n0 & (THW - 1);
    const float* inb = in  + (size_t)bb * CDIM * THW + thw0;
    float*      outb = out + (size_t)bb * CDIM * THW + thw0;

    // ---- stage X tile ([n][c] transpose) + ||x||^2 partials ----
    {
        const int nl = tid & 127;
        const int hf = tid >> 7;
        float s = 0.f;
        #pragma unroll 8
        for (int r = 0; r < 32; ++r) {
            const int c = hf * 32 + r;
            const float x = inb[(size_t)c * THW + nl];
            Xs[nl][c] = x;
            s = fmaf(x, x, s);
        }
        x2p[hf * 128 + nl] = s;
    }
    __syncthreads();

    const int lane = tid & 63;
    const int w    = tid >> 6;      // wave = code quarter (tiles w*16 .. w*16+15)
    const int ln   = lane & 15;
    const int lq   = lane >> 4;

    // ---- B fragments for all 128 queries (fp16 hi/lo), register-resident ----
    half8 Bh[8][2], Bl[8][2];
    #pragma unroll
    for (int qg = 0; qg < 8; ++qg) {
        const int q = qg * 16 + ln;
        #pragma unroll
        for (int ch = 0; ch < 2; ++ch) {
            const float* xp = &Xs[q][ch * 32 + lq * 8];
            const float4 xa = *(const float4*)(xp);
            const float4 xb = *(const float4*)(xp + 4);
            const float xv[8] = {xa.x, xa.y, xa.z, xa.w, xb.x, xb.y, xb.z, xb.w};
            #pragma unroll
            for (int j = 0; j < 8; ++j) {
                const _Float16 h = (_Float16)xv[j];
                const _Float16 l = (_Float16)((xv[j] - (float)h) * 4096.0f);
                Bh[qg][ch][j] = h;
                Bl[qg][ch][j] = l;
            }
        }
    }
    __syncthreads();   // Xs dead; mv/mi alias written after k-loop

    float bestv[8];
    int   besti[8];
    #pragma unroll
    for (int qg = 0; qg < 8; ++qg) { bestv[qg] = 3.4e38f; besti[qg] = 0; }

    const half8* ph = (const half8*)EhF + (size_t)(w * 16) * 128 + lane;
    const half8* pl = (const half8*)ElF + (size_t)(w * 16) * 128 + lane;
    const float* pe = e2 + w * 256 + lq * 4;

    // double-buffered A-fragments + e2
    half8 Ah0[2], Ah1[2], Al0[2], Al1[2];
    float4 e2r[2];
    Ah0[0] = ph[0];  Ah1[0] = ph[64];
    Al0[0] = pl[0];  Al1[0] = pl[64];
    e2r[0] = *(const float4*)pe;

    #pragma unroll 2
    for (int m = 0; m < 16; ++m) {
        const int cur = m & 1;
        const int nxt = cur ^ 1;
        if (m < 15) {
            const size_t o = (size_t)(m + 1) * 128;
            Ah0[nxt] = ph[o];  Ah1[nxt] = ph[o + 64];
            Al0[nxt] = pl[o];  Al1[nxt] = pl[o + 64];
            e2r[nxt] = *(const float4*)(pe + (m + 1) * 16);
        }
        const int t = w * 16 + m;
        const float e2a[4] = {e2r[cur].x, e2r[cur].y, e2r[cur].z, e2r[cur].w};
        #pragma unroll
        for (int qg = 0; qg < 8; ++qg) {
            f32x4 a0 = {0.f, 0.f, 0.f, 0.f};
            f32x4 a1 = {0.f, 0.f, 0.f, 0.f};
            a0 = __builtin_amdgcn_mfma_f32_16x16x32_f16(Ah0[cur], Bh[qg][0], a0, 0, 0, 0);
            a0 = __builtin_amdgcn_mfma_f32_16x16x32_f16(Ah1[cur], Bh[qg][1], a0, 0, 0, 0);
            a1 = __builtin_amdgcn_mfma_f32_16x16x32_f16(Ah0[cur], Bl[qg][0], a1, 0, 0, 0);
            a1 = __builtin_amdgcn_mfma_f32_16x16x32_f16(Al0[cur], Bh[qg][0], a1, 0, 0, 0);
            a1 = __builtin_amdgcn_mfma_f32_16x16x32_f16(Ah1[cur], Bl[qg][1], a1, 0, 0, 0);
            a1 = __builtin_amdgcn_mfma_f32_16x16x32_f16(Al1[cur], Bh[qg][1], a1, 0, 0, 0);
            #pragma unroll
            for (int r = 0; r < 4; ++r) {
                const float d = fmaf(-2.0f, a0[r], fmaf(-4.8828125e-4f, a1[r], e2a[r]));
                const int kg = t * 16 + lq * 4 + r;
                if (d < bestv[qg]) { bestv[qg] = d; besti[qg] = kg; }
            }
        }
    }

    // ---- wave-internal argmin reduce across the 4 row-quads ----
    #pragma unroll
    for (int qg = 0; qg < 8; ++qg) {
        #pragma unroll
        for (int msk = 16; msk <= 32; msk <<= 1) {
            const float ov = __shfl_xor(bestv[qg], msk, 64);
            const int   oi = __shfl_xor(besti[qg], msk, 64);
            if (ov < bestv[qg] || (ov == bestv[qg] && oi < besti[qg])) {
                bestv[qg] = ov; besti[qg] = oi;
            }
        }
    }
    if (lq == 0) {
        #pragma unroll
        for (int qg = 0; qg < 8; ++qg) {
            const int q = qg * 16 + ln;
            mv[w * 128 + q] = bestv[qg];
            mi[w * 128 + q] = besti[qg];
        }
    }
    __syncthreads();

    // ---- merge the 4 code quarters (ascending k => tie-break exact) ----
    float lsum = 0.f;
    if (tid < 128) {
        const int q = tid;
        float v0 = mv[q]; int i0 = mi[q];
        #pragma unroll
        for (int wv = 1; wv < 4; ++wv) {
            const float v = mv[wv * 128 + q]; const int ii = mi[wv * 128 + q];
            if (v < v0 || (v == v0 && ii < i0)) { v0 = v; i0 = ii; }
        }
        idxs[q] = i0;
        out[IDX_OFF + n0 + q] = (float)i0;
        lsum = v0 + x2p[q] + x2p[128 + q];
    }
    #pragma unroll
    for (int off = 32; off > 0; off >>= 1) lsum += __shfl_down(lsum, off, 64);
    if (lane == 0 && w < 2) {
        atomicAdd(&out[LOSS_OFF],     lsum * (1.0f  / (float)QELEMS));
        atomicAdd(&out[LOSS_OFF + 1], lsum * (0.25f / (float)QELEMS));
    }
    __syncthreads();

    // ---- epilogue: gather code rows into LDS, transpose-write ----
    {
        const int q  = tid >> 1;
        const int hf = tid & 1;
        const float* er = emb + (size_t)idxs[q] * CDIM + hf * 32;
        #pragma unroll
        for (int j = 0; j < 8; ++j) {
            const float4 v = *(const float4*)(er + 4 * j);
            *(float4*)(&Q[q][hf * 32 + 4 * j]) = v;
        }
    }
    __syncthreads();
    {
        const int nl = tid & 127;
        const int cb = tid >> 7;
        #pragma unroll 8
        for (int r = 0; r < 32; ++r) {
            const int c = 2 * r + cb;
            outb[(size_t)c * THW + nl] = Q[nl][c];
        }
    }
}

extern "C" void kernel_launch(void* const* d_in, const int* in_sizes, int n_in,
                              void* d_out, int out_size, void* d_ws, size_t ws_size,
                              hipStream_t stream) {
    const float* in  = (const float*)d_in[0];   // (8, 64, 16, 32, 32) fp32
    const float* emb = (const float*)d_in[1];   // (1024, 64) fp32
    float* out = (float*)d_out;
    _Float16* EhF = (_Float16*)d_ws;                        // 64 tiles * 1024 halves
    _Float16* ElF = (_Float16*)((char*)d_ws + 131072);
    float*    e2  = (float*)((char*)d_ws + 262144);         // 1024 floats

    vq_prep<<<KDIM / 16, 256, 0, stream>>>(emb, EhF, ElF, e2, out);
    vq_main<<<NTOT / BN, 256, 0, stream>>>(in, emb, EhF, ElF, e2, out);
}